// Round 1
// baseline (133.360 us; speedup 1.0000x reference)
//
#include <hip/hip_runtime.h>

#define TT 128
#define BB 512
#define DD 512
#define HH 512
#define CC 32
#define NQ 10
#define GC 128      // 4 gates * 32 centres
#define DH 1024     // D + H

typedef _Float16 h2 __attribute__((ext_vector_type(2)));

__device__ __forceinline__ float fdot2f(h2 a, h2 b, float c) {
#if __has_builtin(__builtin_amdgcn_fdot2)
    return __builtin_amdgcn_fdot2(a, b, c, false);
#else
    return c + (float)a.x * (float)b.x + (float)a.y * (float)b.y;
#endif
}

__device__ __forceinline__ float rcpf(float x) {
#if __has_builtin(__builtin_amdgcn_rcpf)
    return __builtin_amdgcn_rcpf(x);
#else
    return 1.f / x;
#endif
}

__device__ __forceinline__ float sigmf(float x) {
    return rcpf(1.f + __expf(-x));
}
__device__ __forceinline__ float tanhfast(float x) {
    // tanh(x) = 1 - 2/(e^{2x}+1); handles +-inf saturation correctly
    return 1.f - 2.f * rcpf(1.f + __expf(2.f * x));
}

__global__ __launch_bounds__(512) void qlstm_kernel(
    const float* __restrict__ inputs,   // [T][B][D]
    const float* __restrict__ centres,  // [4][C][DH]
    const float* __restrict__ lin_w,    // [4][H][C]
    const float* __restrict__ lin_b,    // [4][H]
    float* __restrict__ out)            // outputs [T][B][H] | h [B][H] | c [B][H]
{
    __shared__ _Float16 ldsK[TT * GC];  // 32 KiB: K[t][g*32+c] as fp16
    __shared__ float xs[TT * NQ];       // 5 KiB: x[t][b][0:10]
    __shared__ float cs[GC * NQ];       // 5 KiB: centres[g][c][0:10]

    const int b = blockIdx.x;
    const int tid = threadIdx.x;

    // ---- stage x (first 10 features per t) and centres (first 10 cols) ----
    for (int idx = tid; idx < TT * NQ; idx += 512) {
        int t = idx / NQ, q = idx - t * NQ;
        xs[idx] = inputs[((size_t)t * BB + b) * DD + q];
    }
    for (int idx = tid; idx < GC * NQ; idx += 512) {
        int gc = idx / NQ, q = idx - gc * NQ;
        cs[idx] = centres[(size_t)gc * DH + q];
    }
    __syncthreads();

    // ---- compute quantum-kernel features K[t][gc] for this b ----
    for (int v = tid; v < TT * GC; v += 512) {
        int t = v >> 7, gc = v & 127;
        const float* xr = &xs[t * NQ];
        const float* cr = &cs[gc * NQ];
        float p = 1.f;
        #pragma unroll
        for (int q = 0; q < NQ; ++q)
            p *= fabsf(__cosf(0.5f * (xr[q] - cr[q])));
        ldsK[v] = (_Float16)p;
    }
    __syncthreads();

    // ---- per-thread gate weights in registers (fp16 pairs, 64 VGPRs) ----
    const int h = tid;
    h2 w2[64];
    #pragma unroll
    for (int g = 0; g < 4; ++g) {
        const float* wp = lin_w + ((size_t)g * HH + h) * CC;
        #pragma unroll
        for (int j = 0; j < CC / 2; ++j) {
            h2 ww = { (_Float16)wp[2 * j], (_Float16)wp[2 * j + 1] };
            w2[g * 16 + j] = ww;
        }
    }
    const float bias0 = lin_b[0 * HH + h];
    const float bias1 = lin_b[1 * HH + h];
    const float bias2 = lin_b[2 * HH + h];
    const float bias3 = lin_b[3 * HH + h];

    // ---- sequential recurrence over t (independent per (b,h)) ----
    float cstate = 0.f, hstate = 0.f;
    for (int t = 0; t < TT; ++t) {
        const h2* kr = (const h2*)(ldsK + t * GC);   // broadcast LDS reads
        float a0 = bias0, a1 = bias1, a2 = bias2, a3 = bias3;
        #pragma unroll
        for (int j = 0; j < 16; ++j) {
            a0 = fdot2f(kr[j],      w2[j],      a0);
            a1 = fdot2f(kr[16 + j], w2[16 + j], a1);
            a2 = fdot2f(kr[32 + j], w2[32 + j], a2);
            a3 = fdot2f(kr[48 + j], w2[48 + j], a3);
        }
        float fg = sigmf(a0);
        float ig = sigmf(a1);
        float gg = tanhfast(a2);
        float og = sigmf(a3);
        cstate = fg * cstate + ig * gg;
        hstate = og * tanhfast(cstate);
        out[((size_t)t * BB + b) * HH + h] = hstate;
    }

    float* hout = out + (size_t)TT * BB * HH;
    float* cout = hout + (size_t)BB * HH;
    hout[(size_t)b * HH + h] = hstate;
    cout[(size_t)b * HH + h] = cstate;
}

extern "C" void kernel_launch(void* const* d_in, const int* in_sizes, int n_in,
                              void* d_out, int out_size, void* d_ws, size_t ws_size,
                              hipStream_t stream) {
    const float* inputs  = (const float*)d_in[0];
    const float* centres = (const float*)d_in[1];
    const float* lin_w   = (const float*)d_in[2];
    const float* lin_b   = (const float*)d_in[3];
    float* out = (float*)d_out;

    qlstm_kernel<<<dim3(BB), dim3(512), 0, stream>>>(inputs, centres, lin_w, lin_b, out);
}

// Round 3
// 97.064 us; speedup vs baseline: 1.3739x; 1.3739x over previous
//
#include <hip/hip_runtime.h>

#define TT 128
#define BB 512
#define DD 512
#define HH 512
#define CC 32
#define NQ 10
#define GC 128      // 4 gates * 32 centres
#define DH 1024     // D + H
#define CHUNK 16
#define NCHUNK (TT / CHUNK)

typedef __fp16 h2 __attribute__((ext_vector_type(2)));
typedef __fp16 h4 __attribute__((ext_vector_type(4)));
typedef __fp16 h8 __attribute__((ext_vector_type(8)));
typedef float f4 __attribute__((ext_vector_type(4)));

__device__ __forceinline__ float rcpf(float x) {
    return __builtin_amdgcn_rcpf(x);
}
__device__ __forceinline__ float sigmf(float x) {
    return rcpf(1.f + __expf(-x));
}
__device__ __forceinline__ float tanhfast(float x) {
    // tanh(x) = 1 - 2/(e^{2x}+1); saturates correctly at +-inf
    return 1.f - 2.f * rcpf(1.f + __expf(2.f * x));
}

__global__ __launch_bounds__(512, 2) void qlstm_kernel(
    const float* __restrict__ inputs,   // [T][B][D]
    const float* __restrict__ centres,  // [4][C][DH]
    const float* __restrict__ lin_w,    // [4][H][C]
    const float* __restrict__ lin_b,    // [4][H]
    float* __restrict__ out)            // outputs [T][B][H] | h [B][H] | c [B][H]
{
    __shared__ __fp16 Klds[TT * GC];        // 32 KiB: K[t][gc] f16
    __shared__ __fp16 pre[CHUNK * HH * 4];  // 64 KiB: pre[t_local][h][gate] f16
    __shared__ float xs[TT * NQ];           // 5 KiB
    __shared__ float cs[GC * NQ];           // 5 KiB

    const int b = blockIdx.x;
    const int tid = threadIdx.x;
    const int lane = tid & 63;
    const int w = tid >> 6;       // wave id 0..7; wave w owns h in [w*64, w*64+64)

    // ---- B fragments (weights), held in registers for the whole kernel ----
    // MFMA 16x16x32 B-operand layout: lane holds col n = lane&15,
    // k = (lane>>4)*8 + e (e=0..7, contiguous) -> contiguous c in lin_w[g][h][c].
    h8 bfr[16];   // [g*4 + j], j = N-tile within wave (nt = w*4 + j)
    {
        const int c0 = (lane >> 4) * 8;
        #pragma unroll
        for (int g = 0; g < 4; ++g) {
            #pragma unroll
            for (int j = 0; j < 4; ++j) {
                const int hcol = (w * 4 + j) * 16 + (lane & 15);
                const float* wp = lin_w + (((size_t)g * HH + hcol) * CC + c0);
                f4 lo = *(const f4*)wp;
                f4 hi = *(const f4*)(wp + 4);
                h2 p0 = __builtin_amdgcn_cvt_pkrtz(lo.x, lo.y);
                h2 p1 = __builtin_amdgcn_cvt_pkrtz(lo.z, lo.w);
                h2 p2 = __builtin_amdgcn_cvt_pkrtz(hi.x, hi.y);
                h2 p3 = __builtin_amdgcn_cvt_pkrtz(hi.z, hi.w);
                h8 bb = { p0.x, p0.y, p1.x, p1.y, p2.x, p2.y, p3.x, p3.y };
                bfr[g * 4 + j] = bb;
            }
        }
    }

    const float bias0 = lin_b[0 * HH + tid];
    const float bias1 = lin_b[1 * HH + tid];
    const float bias2 = lin_b[2 * HH + tid];
    const float bias3 = lin_b[3 * HH + tid];

    // ---- stage x (first 10 features per t) and centres (first 10 cols) ----
    for (int idx = tid; idx < TT * NQ; idx += 512) {
        int t = idx / NQ, q = idx - t * NQ;
        xs[idx] = inputs[((size_t)t * BB + b) * DD + q];
    }
    for (int idx = tid; idx < GC * NQ; idx += 512) {
        int gc = idx / NQ, q = idx - gc * NQ;
        cs[idx] = centres[(size_t)gc * DH + q];
    }
    __syncthreads();

    // ---- Phase A: quantum-kernel features K[t][gc] -> LDS f16 ----
    for (int v = tid; v < TT * GC; v += 512) {
        int t = v >> 7, gc = v & 127;
        const float* xr = &xs[t * NQ];
        const float* cr = &cs[gc * NQ];
        float p = 1.f;
        #pragma unroll
        for (int q = 0; q < NQ; ++q)
            p *= fabsf(__cosf(0.5f * (xr[q] - cr[q])));
        Klds[v] = (__fp16)p;
    }
    __syncthreads();

    // ---- Phase B/C: per 16-t chunk, MFMA pre-activations then recurrence ----
    float cstate = 0.f, hstate = 0.f;
    float* op = out + (size_t)b * HH + tid;
    const f4 z4 = {0.f, 0.f, 0.f, 0.f};

    for (int ct = 0; ct < NCHUNK; ++ct) {
        // A fragments: row m = lane&15 (t_local), k = (lane>>4)*8 + e contiguous
        const int arow = ct * CHUNK + (lane & 15);
        h8 afr[4];
        #pragma unroll
        for (int g = 0; g < 4; ++g)
            afr[g] = *(const h8*)&Klds[arow * GC + g * 32 + (lane >> 4) * 8];

        #pragma unroll
        for (int j = 0; j < 4; ++j) {
            f4 a0 = __builtin_amdgcn_mfma_f32_16x16x32_f16(afr[0], bfr[0 * 4 + j], z4, 0, 0, 0);
            f4 a1 = __builtin_amdgcn_mfma_f32_16x16x32_f16(afr[1], bfr[1 * 4 + j], z4, 0, 0, 0);
            f4 a2 = __builtin_amdgcn_mfma_f32_16x16x32_f16(afr[2], bfr[2 * 4 + j], z4, 0, 0, 0);
            f4 a3 = __builtin_amdgcn_mfma_f32_16x16x32_f16(afr[3], bfr[3 * 4 + j], z4, 0, 0, 0);
            // D layout: col = lane&15 (h), row = (lane>>4)*4 + r (t_local)
            const int hcol = (w * 4 + j) * 16 + (lane & 15);
            #pragma unroll
            for (int r = 0; r < 4; ++r) {
                const int tl = (lane >> 4) * 4 + r;
                h2 p01 = __builtin_amdgcn_cvt_pkrtz(a0[r], a1[r]);   // gates f,i
                h2 p23 = __builtin_amdgcn_cvt_pkrtz(a2[r], a3[r]);   // gates g,o
                h4 pv = { p01.x, p01.y, p23.x, p23.y };
                *(h4*)&pre[((size_t)tl * HH + hcol) * 4] = pv;
            }
        }
        __syncthreads();

        // recurrence: thread = h, 16 sequential steps, 1 ds_read_b64 each
        #pragma unroll
        for (int tl = 0; tl < CHUNK; ++tl) {
            h4 v = *(const h4*)&pre[((size_t)tl * HH + tid) * 4];
            float af = bias0 + (float)v.x;
            float ai = bias1 + (float)v.y;
            float ag = bias2 + (float)v.z;
            float ao = bias3 + (float)v.w;
            float fg = sigmf(af);
            float ig = sigmf(ai);
            float gg = tanhfast(ag);
            float og = sigmf(ao);
            cstate = fg * cstate + ig * gg;
            hstate = og * tanhfast(cstate);
            op[(size_t)(ct * CHUNK + tl) * (BB * HH)] = hstate;
        }
        __syncthreads();
    }

    float* hout = out + (size_t)TT * BB * HH;
    float* cout = hout + (size_t)BB * HH;
    hout[(size_t)b * HH + tid] = hstate;
    cout[(size_t)b * HH + tid] = cstate;
}

extern "C" void kernel_launch(void* const* d_in, const int* in_sizes, int n_in,
                              void* d_out, int out_size, void* d_ws, size_t ws_size,
                              hipStream_t stream) {
    const float* inputs  = (const float*)d_in[0];
    const float* centres = (const float*)d_in[1];
    const float* lin_w   = (const float*)d_in[2];
    const float* lin_b   = (const float*)d_in[3];
    float* out = (float*)d_out;

    qlstm_kernel<<<dim3(BB), dim3(512), 0, stream>>>(inputs, centres, lin_w, lin_b, out);
}